// Round 8
// baseline (507.026 us; speedup 1.0000x reference)
//
#include <hip/hip_runtime.h>
#include <math.h>

#define NPT 4096
#define DIM 256
#define NVAR 9
#define INV_TEMP 20.0f
#define THR 0.01f
#define EPSD 1e-12f

typedef unsigned short u16;
typedef __attribute__((ext_vector_type(8))) __bf16 bf16x8;
typedef __attribute__((ext_vector_type(4))) float f32x4;

// ---------- helpers: order-preserving float<->uint for atomicMax on floats ----------
__device__ __forceinline__ unsigned frep(float x) {
    unsigned u = __float_as_uint(x);
    return (u & 0x80000000u) ? ~u : (u | 0x80000000u);
}
__device__ __forceinline__ float funrep(unsigned u) {
    return __uint_as_float((u & 0x80000000u) ? (u ^ 0x80000000u) : ~u);
}

// ---------- bf16 hi/lo split helpers (round-to-nearest-even) ----------
__device__ __forceinline__ u16 f2bf(float x) {
    unsigned u = __float_as_uint(x);
    u += 0x7fffu + ((u >> 16) & 1u);
    return (u16)(u >> 16);
}
__device__ __forceinline__ float bf2f(u16 h) {
    return __uint_as_float(((unsigned)h) << 16);
}
__device__ __forceinline__ void split_hl(float x, u16& h, u16& l) {
    u16 hh = f2bf(x);
    h = hh;
    l = f2bf(x - bf2f(hh));
}

// ---------- async global->LDS, 16B per lane ----------
__device__ __forceinline__ void gl_lds16(const void* g, void* l) {
    __builtin_amdgcn_global_load_lds(
        (const __attribute__((address_space(1))) void*)g,
        (__attribute__((address_space(3))) void*)l, 16, 0, 0);
}

// ---------- fused fp32 -> (hi,lo) bf16 for A, B, protos + fused A/B row norms ----------
#define NA4 (NPT * DIM / 4)          // 262144 float4s for A and for B
#define NP4 (8 * DIM * DIM / 4)      // 131072 float4s for protos
__global__ __launch_bounds__(256) void conv3_kernel(const float* __restrict__ A,
                                                    const float* __restrict__ B,
                                                    const float* __restrict__ Pr,
                                                    u16* __restrict__ Ahi, u16* __restrict__ Alo,
                                                    u16* __restrict__ Bhi, u16* __restrict__ Blo,
                                                    u16* __restrict__ Phi, u16* __restrict__ Plo,
                                                    float* __restrict__ a2,
                                                    float* __restrict__ b2) {
    int i = blockIdx.x * 256 + threadIdx.x;
    const float* src;
    u16 *dh, *dl;
    int j;
    bool isA = false, isB = false;
    if (i < NA4) { src = A; dh = Ahi; dl = Alo; j = i; isA = true; }
    else if (i < 2 * NA4) { src = B; dh = Bhi; dl = Blo; j = i - NA4; isB = true; }
    else if (i < 2 * NA4 + NP4) { src = Pr; dh = Phi; dl = Plo; j = i - 2 * NA4; }
    else return;
    float4 v = ((const float4*)src)[j];
    ushort4 h, l;
    split_hl(v.x, h.x, l.x);
    split_hl(v.y, h.y, l.y);
    split_hl(v.z, h.z, l.z);
    split_hl(v.w, h.w, l.w);
    ((ushort4*)dh)[j] = h;
    ((ushort4*)dl)[j] = l;
    // fused row sumsq of the reconstructed (hi+lo) values; one wave == one row
    if (isA || isB) {
        float x0 = bf2f(h.x) + bf2f(l.x);
        float x1 = bf2f(h.y) + bf2f(l.y);
        float x2 = bf2f(h.z) + bf2f(l.z);
        float x3 = bf2f(h.w) + bf2f(l.w);
        float s = x0 * x0 + x1 * x1 + x2 * x2 + x3 * x3;
#pragma unroll
        for (int o = 32; o; o >>= 1) s += __shfl_xor(s, o);
        if ((threadIdx.x & 63) == 0) {
            int row = j >> 6;
            if (isA) a2[row] = s;
            else b2[row] = s;
        }
    }
}

// ---------- steering via bf16 MFMA hi/lo (3 passes): S_k = A0 * M_k^T ----------
// grid (32, 2, 8): 128x128 tile over (M=4096 rows, E=256 cols), proto k -> slot k+1
// Also accumulates row sumsq into a2 slot k+1 (fused norm computation).
__global__ __launch_bounds__(256, 2) void steer_mfma_kernel(
    const u16* __restrict__ A0h, const u16* __restrict__ A0l,
    const u16* __restrict__ Ph, const u16* __restrict__ Pl,
    u16* __restrict__ outH, u16* __restrict__ outL,
    float* __restrict__ a2out) {
    __shared__ u16 lds[32768];  // 64 KB: Ah, Al, Bh, Bl each 128x64
    u16* LAh = lds;
    u16* LAl = lds + 8192;
    u16* LBh = lds + 16384;
    u16* LBl = lds + 24576;

    const int tid = threadIdx.x, lane = tid & 63, wave = tid >> 6;
    const int l15 = lane & 15, lg = lane >> 4;
    const int wr = (wave >> 1) * 64, wc = (wave & 1) * 64;
    const int rb = blockIdx.x * 128;
    const int eb = blockIdx.y * 128;
    const int k = blockIdx.z;
    const u16* Bh_g = Ph + (size_t)k * DIM * DIM;
    const u16* Bl_g = Pl + (size_t)k * DIM * DIM;
    const int s_row = tid >> 3;                 // 0..31
    const int s_ch = tid & 7;                   // LDS chunk
    const int s_gch = s_ch ^ (s_row & 7);       // swizzled global chunk
    const int c0 = lg ^ (l15 & 7);              // per-lane read chunk xor

    f32x4 acc[4][4];
#pragma unroll
    for (int m = 0; m < 4; ++m)
#pragma unroll
        for (int n = 0; n < 4; ++n) acc[m][n] = 0.0f;

    for (int kb = 0; kb < 4; ++kb) {
        const int k0 = kb * 64;
        __syncthreads();
#pragma unroll
        for (int r = 0; r < 4; ++r) {
            int row = r * 32 + s_row;
            size_t ga = (size_t)(rb + row) * DIM + k0 + s_gch * 8;
            size_t gb = (size_t)(eb + row) * DIM + k0 + s_gch * 8;
            int lo = row * 64 + s_ch * 8;
            gl_lds16(A0h + ga, &LAh[lo]);
            gl_lds16(A0l + ga, &LAl[lo]);
            gl_lds16(Bh_g + gb, &LBh[lo]);
            gl_lds16(Bl_g + gb, &LBl[lo]);
        }
        __syncthreads();
#pragma unroll
        for (int ks = 0; ks < 2; ++ks) {
            const int cx = (c0 ^ (ks << 2)) * 8;
            bf16x8 ah[4], al[4], bh[4], bl[4];
#pragma unroll
            for (int m = 0; m < 4; ++m) {
                int ro = (wr + m * 16 + l15) * 64 + cx;
                ah[m] = *(const bf16x8*)&LAh[ro];
                al[m] = *(const bf16x8*)&LAl[ro];
            }
#pragma unroll
            for (int n = 0; n < 4; ++n) {
                int ro = (wc + n * 16 + l15) * 64 + cx;
                bh[n] = *(const bf16x8*)&LBh[ro];
                bl[n] = *(const bf16x8*)&LBl[ro];
            }
#pragma unroll
            for (int m = 0; m < 4; ++m)
#pragma unroll
                for (int n = 0; n < 4; ++n)
                    acc[m][n] = __builtin_amdgcn_mfma_f32_16x16x32_bf16(ah[m], bh[n], acc[m][n], 0, 0, 0);
#pragma unroll
            for (int m = 0; m < 4; ++m)
#pragma unroll
                for (int n = 0; n < 4; ++n)
                    acc[m][n] = __builtin_amdgcn_mfma_f32_16x16x32_bf16(al[m], bh[n], acc[m][n], 0, 0, 0);
#pragma unroll
            for (int m = 0; m < 4; ++m)
#pragma unroll
                for (int n = 0; n < 4; ++n)
                    acc[m][n] = __builtin_amdgcn_mfma_f32_16x16x32_bf16(ah[m], bl[n], acc[m][n], 0, 0, 0);
        }
    }
    // epilogue: split to hi/lo, store into variant slot k+1; fused row sumsq -> a2
#pragma unroll
    for (int m = 0; m < 4; ++m)
#pragma unroll
        for (int j = 0; j < 4; ++j) {
            size_t row = (size_t)(k + 1) * NPT + rb + wr + m * 16 + lg * 4 + j;
            float s2 = 0.f;
#pragma unroll
            for (int n = 0; n < 4; ++n) {
                float s = acc[m][n][j];
                s2 += s * s;
                u16 h, l;
                split_hl(s, h, l);
                size_t idx = row * DIM + eb + wc + n * 16 + l15;
                outH[idx] = h;
                outL[idx] = l;
            }
            s2 += __shfl_xor(s2, 1);
            s2 += __shfl_xor(s2, 2);
            s2 += __shfl_xor(s2, 4);
            s2 += __shfl_xor(s2, 8);
            if (l15 == 0) atomicAdd(&a2out[row], s2);
        }
}

// ---------- main fused corr via bf16 MFMA hi/lo (3 terms), 9 variants ----------
// grid (32,32); XCD -> 8x16 rectangle for L2 residency of the B slice.
// K=32 chunks, double-buffered LDS prefetch: STAGE(next) || compute(cur), one
// barrier per chunk (syncthreads drains vmcnt -> staged buffer ready).
// Epilogue computes per-block softmax partials (max,sum) per row/col.
__global__ __launch_bounds__(256, 2) void corr_mfma_kernel(
    const u16* __restrict__ Ahi, const u16* __restrict__ Alo,
    const u16* __restrict__ Bhi, const u16* __restrict__ Blo,
    const float* __restrict__ a2, const float* __restrict__ b2,
    float* __restrict__ cOut, unsigned* __restrict__ rm_rep, unsigned* __restrict__ cm_rep,
    float* __restrict__ pMaxR, float* __restrict__ pSumR,
    float* __restrict__ pMaxC, float* __restrict__ pSumC) {
    __shared__ u16 lds[32768];  // 64 KB = 2 bufs x 4 matrices x [128][32] u16

    const int tid = threadIdx.x, lane = tid & 63, wave = tid >> 6;
    const int l15 = lane & 15, lg = lane >> 4;
    const int wr = (wave >> 1) * 64, wc = (wave & 1) * 64;
    // XCD-aware swizzle: each of 8 XCDs owns an 8rb x 16cb rectangle.
    int wg = blockIdx.y * 32 + blockIdx.x;
    const int xcd = wg & 7, idx8 = wg >> 3;
    const int rbIdx = ((xcd >> 1) << 3) + (idx8 >> 4);   // 0..31
    const int cbIdx = ((xcd & 1) << 4) + (idx8 & 15);    // 0..31
    const int rb = rbIdx << 7;
    const int cb = cbIdx << 7;
    const int s_row = tid >> 2;        // 0..63
    const int s_seg = (tid & 3) * 8;   // u16 offset within a 32-col row

    float b2c[4];
#pragma unroll
    for (int n = 0; n < 4; ++n) b2c[n] = b2[cb + wc + n * 16 + l15];

    f32x4 zmin[4][4];
#pragma unroll
    for (int m = 0; m < 4; ++m)
#pragma unroll
        for (int n = 0; n < 4; ++n) zmin[m][n] = 3.402823466e38f;

    // stage chunk `it` (it = v*8 + kb, 32 k-cols) into buffer `buf`
    auto STAGE = [&](int it, int buf) {
        const int v = it >> 3, kb = it & 7, k0 = kb * 32;
        const u16* Ah_g = Ahi + (size_t)v * NPT * DIM;
        const u16* Al_g = Alo + (size_t)v * NPT * DIM;
        u16* base = lds + buf * 16384;
#pragma unroll
        for (int r = 0; r < 2; ++r) {
            int row = s_row + 64 * r;
            size_t ga = (size_t)(rb + row) * DIM + k0 + s_seg;
            size_t gb = (size_t)(cb + row) * DIM + k0 + s_seg;
            int lo = row * 32 + s_seg;
            gl_lds16(Ah_g + ga, base + lo);
            gl_lds16(Al_g + ga, base + 4096 + lo);
            gl_lds16(Bhi + gb, base + 8192 + lo);
            gl_lds16(Blo + gb, base + 12288 + lo);
        }
    };

    STAGE(0, 0);
    __syncthreads();  // drains vmcnt(0): buffer 0 ready
    int buf = 0;

    for (int v = 0; v < NVAR; ++v) {
        f32x4 acc[4][4];
#pragma unroll
        for (int m = 0; m < 4; ++m)
#pragma unroll
            for (int n = 0; n < 4; ++n) acc[m][n] = 0.0f;

        for (int kb = 0; kb < 8; ++kb) {
            const int it = v * 8 + kb;
            if (it + 1 < NVAR * 8) STAGE(it + 1, buf ^ 1);
            // compute current buffer
            const u16* base = lds + buf * 16384;
            bf16x8 ah[4], al[4], bh[4], bl[4];
#pragma unroll
            for (int m = 0; m < 4; ++m) {
                int ro = (wr + m * 16 + l15) * 32 + lg * 8;
                ah[m] = *(const bf16x8*)&base[ro];
                al[m] = *(const bf16x8*)&base[4096 + ro];
            }
#pragma unroll
            for (int n = 0; n < 4; ++n) {
                int ro = (wc + n * 16 + l15) * 32 + lg * 8;
                bh[n] = *(const bf16x8*)&base[8192 + ro];
                bl[n] = *(const bf16x8*)&base[12288 + ro];
            }
#pragma unroll
            for (int m = 0; m < 4; ++m)
#pragma unroll
                for (int n = 0; n < 4; ++n)
                    acc[m][n] = __builtin_amdgcn_mfma_f32_16x16x32_bf16(ah[m], bh[n], acc[m][n], 0, 0, 0);
#pragma unroll
            for (int m = 0; m < 4; ++m)
#pragma unroll
                for (int n = 0; n < 4; ++n)
                    acc[m][n] = __builtin_amdgcn_mfma_f32_16x16x32_bf16(al[m], bh[n], acc[m][n], 0, 0, 0);
#pragma unroll
            for (int m = 0; m < 4; ++m)
#pragma unroll
                for (int n = 0; n < 4; ++n)
                    acc[m][n] = __builtin_amdgcn_mfma_f32_16x16x32_bf16(ah[m], bl[n], acc[m][n], 0, 0, 0);
            __syncthreads();  // all reads of buf done; staged buf^1 complete (vmcnt 0)
            buf ^= 1;
        }
        // fold: d2 = a2 + b2 - 2*dot, clamp, min over variants
#pragma unroll
        for (int m = 0; m < 4; ++m) {
            float4 a4 = *(const float4*)&a2[(size_t)v * NPT + rb + wr + m * 16 + lg * 4];
            const float* a4p = (const float*)&a4;
#pragma unroll
            for (int n = 0; n < 4; ++n)
#pragma unroll
                for (int j = 0; j < 4; ++j) {
                    float d2 = fmaxf(a4p[j] + b2c[n] - 2.0f * acc[m][n][j], 0.0f);
                    zmin[m][n][j] = fminf(zmin[m][n][j], d2);
                }
        }
    }

    // ---- epilogue pass 1: c = -20*sqrt(zmin+eps), store C, block-local row/col max ----
    unsigned* redR = (unsigned*)lds;          // 128
    unsigned* redC = redR + 128;              // 128
    float* bsumR = (float*)(redC + 128);      // 128
    float* bsumC = bsumR + 128;               // 128
    __syncthreads();
    if (tid < 128) { redR[tid] = 0u; redC[tid] = 0u; bsumR[tid] = 0.f; bsumC[tid] = 0.f; }
    __syncthreads();

    float colmax[4] = {-3.402823466e38f, -3.402823466e38f, -3.402823466e38f, -3.402823466e38f};
#pragma unroll
    for (int m = 0; m < 4; ++m) {
#pragma unroll
        for (int j = 0; j < 4; ++j) {
            int row = rb + wr + m * 16 + lg * 4 + j;
            float rmax = -3.402823466e38f;
#pragma unroll
            for (int n = 0; n < 4; ++n) {
                float c = -INV_TEMP * sqrtf(zmin[m][n][j] + EPSD);
                cOut[(size_t)row * NPT + cb + wc + n * 16 + l15] = c;
                rmax = fmaxf(rmax, c);
                colmax[n] = fmaxf(colmax[n], c);
            }
            atomicMax(&redR[wr + m * 16 + lg * 4 + j], frep(rmax));
        }
    }
#pragma unroll
    for (int n = 0; n < 4; ++n)
        atomicMax(&redC[wc + n * 16 + l15], frep(colmax[n]));
    __syncthreads();

    // ---- epilogue pass 2: block-local exp-sums relative to block max ----
    float bmc[4], colS[4];
#pragma unroll
    for (int n = 0; n < 4; ++n) {
        bmc[n] = funrep(redC[wc + n * 16 + l15]);
        colS[n] = 0.f;
    }
#pragma unroll
    for (int m = 0; m < 4; ++m) {
#pragma unroll
        for (int j = 0; j < 4; ++j) {
            int lr = wr + m * 16 + lg * 4 + j;
            float bm = funrep(redR[lr]);
            float s = 0.f;
#pragma unroll
            for (int n = 0; n < 4; ++n) {
                float c = -INV_TEMP * sqrtf(zmin[m][n][j] + EPSD);
                s += __expf(c - bm);
                colS[n] += __expf(c - bmc[n]);
            }
            // reduce over the 16-lane l15 group (covers 64 cols of this row)
            s += __shfl_xor(s, 1);
            s += __shfl_xor(s, 2);
            s += __shfl_xor(s, 4);
            s += __shfl_xor(s, 8);
            if (l15 == 0) atomicAdd(&bsumR[lr], s);
        }
    }
#pragma unroll
    for (int n = 0; n < 4; ++n) {
        float s = colS[n];
        // reduce over lg (lanes differing in bits 4,5)
        s += __shfl_xor(s, 16);
        s += __shfl_xor(s, 32);
        if (lg == 0) atomicAdd(&bsumC[wc + n * 16 + l15], s);
    }
    __syncthreads();

    // ---- epilogue pass 3: global max atomics + per-block partial writes ----
    if (tid < 128) {
        atomicMax(&rm_rep[rb + tid], redR[tid]);
        pMaxR[(size_t)cbIdx * NPT + rb + tid] = funrep(redR[tid]);
        pSumR[(size_t)cbIdx * NPT + rb + tid] = bsumR[tid];
    } else {
        int t = tid - 128;
        atomicMax(&cm_rep[cb + t], redC[t]);
        pMaxC[(size_t)rbIdx * NPT + cb + t] = funrep(redC[t]);
        pSumC[(size_t)rbIdx * NPT + cb + t] = bsumC[t];
    }
}

// ---------- combine per-block partials into rowsum/colsum ----------
__global__ __launch_bounds__(256) void combine_kernel(const unsigned* __restrict__ rm_rep,
                                                      const unsigned* __restrict__ cm_rep,
                                                      const float* __restrict__ pMaxR,
                                                      const float* __restrict__ pSumR,
                                                      const float* __restrict__ pMaxC,
                                                      const float* __restrict__ pSumC,
                                                      float* __restrict__ rowsum,
                                                      float* __restrict__ colsum) {
    int idx = (blockIdx.x & 15) * 256 + threadIdx.x;
    if (blockIdx.x < 16) {
        float gm = funrep(rm_rep[idx]);
        float s = 0.f;
#pragma unroll
        for (int b = 0; b < 32; ++b)
            s += pSumR[(size_t)b * NPT + idx] * __expf(pMaxR[(size_t)b * NPT + idx] - gm);
        rowsum[idx] = s;
    } else {
        float gm = funrep(cm_rep[idx]);
        float s = 0.f;
#pragma unroll
        for (int b = 0; b < 32; ++b)
            s += pSumC[(size_t)b * NPT + idx] * __expf(pMaxC[(size_t)b * NPT + idx] - gm);
        colsum[idx] = s;
    }
}

// ======================= streaming epilogue =======================
// grid 1024 blocks; block owns 256 cols x 64 rows. Thread: 4 consecutive cols
// (c0 + lane*4), rows r0 + it*4 + wv, it=0..15. float4 I/O throughout.

// pass A: P = exp(2c - cm - rm)/(cs*rs) in place, track row/col max of P
__global__ __launch_bounds__(256) void pmax_kernel(float* __restrict__ C,
                                                   const unsigned* __restrict__ rm_rep,
                                                   const unsigned* __restrict__ cm_rep,
                                                   const float* __restrict__ rowsum,
                                                   const float* __restrict__ colsum,
                                                   unsigned* __restrict__ rmp_rep,
                                                   unsigned* __restrict__ cmp_rep) {
    const int tid = threadIdx.x, lane = tid & 63, wv = tid >> 6;
    const int c0 = (blockIdx.x & 15) * 256;
    const int r0 = (blockIdx.x >> 4) * 64;
    const int colq = (c0 >> 2) + lane;
    __shared__ float rmbuf[64], rrbuf[64];
    __shared__ float pmLds[64 * 65];
    __shared__ float qred[256];
    __shared__ float cred[4][256];
    if (tid < 64) {
        rmbuf[tid] = funrep(rm_rep[r0 + tid]);
        rrbuf[tid] = 1.0f / rowsum[r0 + tid];
    }
    uint4 cmr = ((const uint4*)cm_rep)[colq];
    float cm0 = funrep(cmr.x), cm1 = funrep(cmr.y), cm2 = funrep(cmr.z), cm3 = funrep(cmr.w);
    float4 csv = ((const float4*)colsum)[colq];
    float rc0 = 1.0f / csv.x, rc1 = 1.0f / csv.y, rc2 = 1.0f / csv.z, rc3 = 1.0f / csv.w;
    __syncthreads();
    float4 cmax = make_float4(-1.f, -1.f, -1.f, -1.f);
#pragma unroll
    for (int it = 0; it < 16; ++it) {
        int lr = it * 4 + wv;
        int r = r0 + lr;
        size_t idx = (size_t)r * (NPT / 4) + colq;
        float4 cv = ((const float4*)C)[idx];
        float rm = rmbuf[lr];
        float rr = rrbuf[lr];
        float4 p;
        p.x = __expf(2.0f * cv.x - cm0 - rm) * (rc0 * rr);
        p.y = __expf(2.0f * cv.y - cm1 - rm) * (rc1 * rr);
        p.z = __expf(2.0f * cv.z - cm2 - rm) * (rc2 * rr);
        p.w = __expf(2.0f * cv.w - cm3 - rm) * (rc3 * rr);
        ((float4*)C)[idx] = p;
        pmLds[lr * 65 + lane] = fmaxf(fmaxf(p.x, p.y), fmaxf(p.z, p.w));
        cmax.x = fmaxf(cmax.x, p.x);
        cmax.y = fmaxf(cmax.y, p.y);
        cmax.z = fmaxf(cmax.z, p.z);
        cmax.w = fmaxf(cmax.w, p.w);
    }
    cred[wv][lane * 4 + 0] = cmax.x;
    cred[wv][lane * 4 + 1] = cmax.y;
    cred[wv][lane * 4 + 2] = cmax.z;
    cred[wv][lane * 4 + 3] = cmax.w;
    __syncthreads();
    {
        int row = tid & 63, q = tid >> 6;
        float m = -1.f;
#pragma unroll
        for (int i = 0; i < 16; ++i) m = fmaxf(m, pmLds[row * 65 + q * 16 + i]);
        qred[row * 4 + q] = m;
    }
    float mc = fmaxf(fmaxf(cred[0][tid], cred[1][tid]), fmaxf(cred[2][tid], cred[3][tid]));
    atomicMax(&cmp_rep[c0 + tid], frep(mc));
    __syncthreads();
    if (tid < 64) {
        float m = fmaxf(fmaxf(qred[tid * 4 + 0], qred[tid * 4 + 1]),
                        fmaxf(qred[tid * 4 + 2], qred[tid * 4 + 3]));
        atomicMax(&rmp_rep[r0 + tid], frep(m));
    }
}

// pass B: mask write + first-occurrence argmax (atomicMin on col index)
__global__ __launch_bounds__(256) void maskarg_kernel(const float* __restrict__ P,
                                                      const unsigned* __restrict__ rmp_rep,
                                                      const unsigned* __restrict__ cmp_rep,
                                                      float* __restrict__ maskOut,
                                                      int* __restrict__ argJ) {
    const int tid = threadIdx.x, lane = tid & 63, wv = tid >> 6;
    const int c0 = (blockIdx.x & 15) * 256;
    const int r0 = (blockIdx.x >> 4) * 64;
    const int colq = (c0 >> 2) + lane;
    const int col4 = c0 + lane * 4;
    __shared__ float rpbuf[64];
    __shared__ int candLds[64 * 65];
    __shared__ int qredi[256];
    if (tid < 64) rpbuf[tid] = funrep(rmp_rep[r0 + tid]);
    uint4 cpr = ((const uint4*)cmp_rep)[colq];
    float cp0 = funrep(cpr.x), cp1 = funrep(cpr.y), cp2 = funrep(cpr.z), cp3 = funrep(cpr.w);
    __syncthreads();
#pragma unroll
    for (int it = 0; it < 16; ++it) {
        int lr = it * 4 + wv;
        int r = r0 + lr;
        size_t idx = (size_t)r * (NPT / 4) + colq;
        float4 p = ((const float4*)P)[idx];
        float rmp = rpbuf[lr];
        float4 m;
        m.x = (p.x == rmp && p.x == cp0 && p.x > THR) ? 1.f : 0.f;
        m.y = (p.y == rmp && p.y == cp1 && p.y > THR) ? 1.f : 0.f;
        m.z = (p.z == rmp && p.z == cp2 && p.z > THR) ? 1.f : 0.f;
        m.w = (p.w == rmp && p.w == cp3 && p.w > THR) ? 1.f : 0.f;
        ((float4*)maskOut)[idx] = m;
        int cand = 0x7fffffff;
        if (p.w == rmp) cand = col4 + 3;
        if (p.z == rmp) cand = col4 + 2;
        if (p.y == rmp) cand = col4 + 1;
        if (p.x == rmp) cand = col4 + 0;
        candLds[lr * 65 + lane] = cand;
    }
    __syncthreads();
    {
        int row = tid & 63, q = tid >> 6;
        int m = 0x7fffffff;
#pragma unroll
        for (int i = 0; i < 16; ++i) m = min(m, candLds[row * 65 + q * 16 + i]);
        qredi[row * 4 + q] = m;
    }
    __syncthreads();
    if (tid < 64) {
        int m = min(min(qredi[tid * 4 + 0], qredi[tid * 4 + 1]),
                    min(qredi[tid * 4 + 2], qredi[tid * 4 + 3]));
        atomicMin(&argJ[r0 + tid], m);
    }
}

// pass C: valid flag + matched keypoints (tiny)
__global__ __launch_bounds__(256) void valid_kernel(const float* __restrict__ P,
                                                    const unsigned* __restrict__ cmp_rep,
                                                    const int* __restrict__ argJ,
                                                    const float* __restrict__ kpB,
                                                    float* __restrict__ validOut,
                                                    float* __restrict__ matchOut) {
    int n = blockIdx.x * 256 + threadIdx.x;
    int j = argJ[n];
    float pj = P[(size_t)n * NPT + j];
    bool v = (pj == funrep(cmp_rep[j])) && (pj > THR);
    validOut[n] = v ? 1.f : 0.f;
    matchOut[2 * n + 0] = kpB[2 * j + 0];
    matchOut[2 * n + 1] = kpB[2 * j + 1];
}

extern "C" void kernel_launch(void* const* d_in, const int* in_sizes, int n_in,
                              void* d_out, int out_size, void* d_ws, size_t ws_size,
                              hipStream_t stream) {
    const float* dA     = (const float*)d_in[1];  // descriptions_A [4096,256]
    const float* kpB    = (const float*)d_in[2];  // keypoints_B    [4096,2]
    const float* dB     = (const float*)d_in[3];  // descriptions_B [4096,256]
    const float* protos = (const float*)d_in[4];  // prototype_mats [8,256,256]

    float* P      = (float*)d_out;                  // 4096*4096
    float* maskO  = P + (size_t)NPT * NPT;          // 4096*4096
    float* validO = maskO + (size_t)NPT * NPT;      // 4096
    float* matchO = validO + NPT;                   // 4096*2

    // bf16 hi/lo buffers + softmax partials parked in the mask region
    // (mask written only by maskarg at the very end): ~46 MB < 64 MB
    u16* Ahi = (u16*)maskO;                         // 9*4096*256
    u16* Alo = Ahi + (size_t)NVAR * NPT * DIM;
    u16* Bhi = Alo + (size_t)NVAR * NPT * DIM;      // 4096*256
    u16* Blo = Bhi + (size_t)NPT * DIM;
    u16* Phi = Blo + (size_t)NPT * DIM;             // 8*256*256
    u16* Plo = Phi + (size_t)8 * DIM * DIM;
    float* pMaxR = (float*)(Plo + (size_t)8 * DIM * DIM);  // [32][4096]
    float* pSumR = pMaxR + 32 * NPT;
    float* pMaxC = pSumR + 32 * NPT;
    float* pSumC = pMaxC + 32 * NPT;

    // small stats live in ws (~300 KB)
    float* ws      = (float*)d_ws;
    float* a2      = ws;                 // 9*4096
    float* b2      = a2 + NVAR * NPT;    // 4096
    unsigned* rm   = (unsigned*)(b2 + NPT);   // atomic-max targets, contiguous x4
    unsigned* cm   = rm + NPT;
    unsigned* rmp  = cm + NPT;
    unsigned* cmp  = rmp + NPT;
    float* rs      = (float*)(cmp + NPT);
    float* cs      = rs + NPT;
    int* argJ      = (int*)(cs + NPT);

    // zero atomic targets: a2 slots 1..8 (steer atomicAdds), the 4 max arrays;
    // argJ to big sentinel (0x7f7f7f7f)
    hipMemsetAsync(a2 + NPT, 0, 8 * NPT * sizeof(float), stream);
    hipMemsetAsync(rm, 0, 4 * NPT * sizeof(unsigned), stream);
    hipMemsetAsync(argJ, 0x7f, NPT * sizeof(int), stream);

    conv3_kernel<<<2560, 256, 0, stream>>>(dA, dB, protos, Ahi, Alo, Bhi, Blo, Phi, Plo, a2, b2);
    steer_mfma_kernel<<<dim3(32, 2, 8), 256, 0, stream>>>(Ahi, Alo, Phi, Plo, Ahi, Alo, a2);
    corr_mfma_kernel<<<dim3(32, 32), 256, 0, stream>>>(Ahi, Alo, Bhi, Blo, a2, b2, P, rm, cm,
                                                       pMaxR, pSumR, pMaxC, pSumC);
    combine_kernel<<<32, 256, 0, stream>>>(rm, cm, pMaxR, pSumR, pMaxC, pSumC, rs, cs);
    pmax_kernel<<<1024, 256, 0, stream>>>(P, rm, cm, rs, cs, rmp, cmp);
    maskarg_kernel<<<1024, 256, 0, stream>>>(P, rmp, cmp, maskO, argJ);
    valid_kernel<<<16, 256, 0, stream>>>(P, cmp, argJ, kpB, validO, matchO);
}

// Round 9
// 414.902 us; speedup vs baseline: 1.2220x; 1.2220x over previous
//
#include <hip/hip_runtime.h>
#include <math.h>

#define NPT 4096
#define DIM 256
#define NVAR 9
#define INV_TEMP 20.0f
#define THR 0.01f
#define EPSD 1e-12f

typedef unsigned short u16;
typedef __attribute__((ext_vector_type(8))) __bf16 bf16x8;
typedef __attribute__((ext_vector_type(4))) float f32x4;

// ---------- helpers: order-preserving float<->uint for atomicMax on floats ----------
__device__ __forceinline__ unsigned frep(float x) {
    unsigned u = __float_as_uint(x);
    return (u & 0x80000000u) ? ~u : (u | 0x80000000u);
}
__device__ __forceinline__ float funrep(unsigned u) {
    return __uint_as_float((u & 0x80000000u) ? (u ^ 0x80000000u) : ~u);
}

// ---------- bf16 hi/lo split helpers (round-to-nearest-even) ----------
__device__ __forceinline__ u16 f2bf(float x) {
    unsigned u = __float_as_uint(x);
    u += 0x7fffu + ((u >> 16) & 1u);
    return (u16)(u >> 16);
}
__device__ __forceinline__ float bf2f(u16 h) {
    return __uint_as_float(((unsigned)h) << 16);
}
__device__ __forceinline__ void split_hl(float x, u16& h, u16& l) {
    u16 hh = f2bf(x);
    h = hh;
    l = f2bf(x - bf2f(hh));
}

// ---------- async global->LDS, 16B per lane ----------
__device__ __forceinline__ void gl_lds16(const void* g, void* l) {
    __builtin_amdgcn_global_load_lds(
        (const __attribute__((address_space(1))) void*)g,
        (__attribute__((address_space(3))) void*)l, 16, 0, 0);
}

// ---------- fused fp32 -> (hi,lo) bf16 for A, B, protos + row norms + ws zero-init ----------
#define NA4 (NPT * DIM / 4)          // 262144 float4s for A and for B
#define NP4 (8 * DIM * DIM / 4)      // 131072 float4s for protos
#define ZBASE (2 * NA4 + NP4)        // 655360: start of zero-init work items
__global__ __launch_bounds__(256) void conv3_kernel(const float* __restrict__ A,
                                                    const float* __restrict__ B,
                                                    const float* __restrict__ Pr,
                                                    u16* __restrict__ Ahi, u16* __restrict__ Alo,
                                                    u16* __restrict__ Bhi, u16* __restrict__ Blo,
                                                    u16* __restrict__ Phi, u16* __restrict__ Plo,
                                                    float* __restrict__ a2,
                                                    float* __restrict__ b2,
                                                    unsigned* __restrict__ zero4,  // rm,cm,rmp,cmp
                                                    int* __restrict__ argJ) {
    int i = blockIdx.x * 256 + threadIdx.x;
    if (i >= ZBASE) {
        int z = i - ZBASE;
        if (z < 8 * NPT) a2[NPT + z] = 0.f;                   // a2 slots 1..8
        else if (z < 12 * NPT) zero4[z - 8 * NPT] = 0u;       // rm|cm|rmp|cmp
        else if (z < 13 * NPT) argJ[z - 12 * NPT] = 0x7f7f7f7f;
        return;
    }
    const float* src;
    u16 *dh, *dl;
    int j;
    bool isA = false, isB = false;
    if (i < NA4) { src = A; dh = Ahi; dl = Alo; j = i; isA = true; }
    else if (i < 2 * NA4) { src = B; dh = Bhi; dl = Blo; j = i - NA4; isB = true; }
    else { src = Pr; dh = Phi; dl = Plo; j = i - 2 * NA4; }
    float4 v = ((const float4*)src)[j];
    ushort4 h, l;
    split_hl(v.x, h.x, l.x);
    split_hl(v.y, h.y, l.y);
    split_hl(v.z, h.z, l.z);
    split_hl(v.w, h.w, l.w);
    ((ushort4*)dh)[j] = h;
    ((ushort4*)dl)[j] = l;
    // fused row sumsq of the reconstructed (hi+lo) values; one wave == one row
    if (isA || isB) {
        float x0 = bf2f(h.x) + bf2f(l.x);
        float x1 = bf2f(h.y) + bf2f(l.y);
        float x2 = bf2f(h.z) + bf2f(l.z);
        float x3 = bf2f(h.w) + bf2f(l.w);
        float s = x0 * x0 + x1 * x1 + x2 * x2 + x3 * x3;
#pragma unroll
        for (int o = 32; o; o >>= 1) s += __shfl_xor(s, o);
        if ((threadIdx.x & 63) == 0) {
            int row = j >> 6;
            if (isA) a2[row] = s;
            else b2[row] = s;
        }
    }
}

// ---------- steering via bf16 MFMA hi/lo (3 passes): S_k = A0 * M_k^T ----------
// grid (32, 2, 8): 128x128 tile over (M=4096 rows, E=256 cols), proto k -> slot k+1
// Also accumulates row sumsq into a2 slot k+1 (fused norm computation).
__global__ __launch_bounds__(256, 2) void steer_mfma_kernel(
    const u16* __restrict__ A0h, const u16* __restrict__ A0l,
    const u16* __restrict__ Ph, const u16* __restrict__ Pl,
    u16* __restrict__ outH, u16* __restrict__ outL,
    float* __restrict__ a2out) {
    __shared__ u16 lds[32768];  // 64 KB: Ah, Al, Bh, Bl each 128x64
    u16* LAh = lds;
    u16* LAl = lds + 8192;
    u16* LBh = lds + 16384;
    u16* LBl = lds + 24576;

    const int tid = threadIdx.x, lane = tid & 63, wave = tid >> 6;
    const int l15 = lane & 15, lg = lane >> 4;
    const int wr = (wave >> 1) * 64, wc = (wave & 1) * 64;
    const int rb = blockIdx.x * 128;
    const int eb = blockIdx.y * 128;
    const int k = blockIdx.z;
    const u16* Bh_g = Ph + (size_t)k * DIM * DIM;
    const u16* Bl_g = Pl + (size_t)k * DIM * DIM;
    const int s_row = tid >> 3;                 // 0..31
    const int s_ch = tid & 7;                   // LDS chunk
    const int s_gch = s_ch ^ (s_row & 7);       // swizzled global chunk
    const int c0 = lg ^ (l15 & 7);              // per-lane read chunk xor

    f32x4 acc[4][4];
#pragma unroll
    for (int m = 0; m < 4; ++m)
#pragma unroll
        for (int n = 0; n < 4; ++n) acc[m][n] = 0.0f;

    for (int kb = 0; kb < 4; ++kb) {
        const int k0 = kb * 64;
        __syncthreads();
#pragma unroll
        for (int r = 0; r < 4; ++r) {
            int row = r * 32 + s_row;
            size_t ga = (size_t)(rb + row) * DIM + k0 + s_gch * 8;
            size_t gb = (size_t)(eb + row) * DIM + k0 + s_gch * 8;
            int lo = row * 64 + s_ch * 8;
            gl_lds16(A0h + ga, &LAh[lo]);
            gl_lds16(A0l + ga, &LAl[lo]);
            gl_lds16(Bh_g + gb, &LBh[lo]);
            gl_lds16(Bl_g + gb, &LBl[lo]);
        }
        __syncthreads();
#pragma unroll
        for (int ks = 0; ks < 2; ++ks) {
            const int cx = (c0 ^ (ks << 2)) * 8;
            bf16x8 ah[4], al[4], bh[4], bl[4];
#pragma unroll
            for (int m = 0; m < 4; ++m) {
                int ro = (wr + m * 16 + l15) * 64 + cx;
                ah[m] = *(const bf16x8*)&LAh[ro];
                al[m] = *(const bf16x8*)&LAl[ro];
            }
#pragma unroll
            for (int n = 0; n < 4; ++n) {
                int ro = (wc + n * 16 + l15) * 64 + cx;
                bh[n] = *(const bf16x8*)&LBh[ro];
                bl[n] = *(const bf16x8*)&LBl[ro];
            }
#pragma unroll
            for (int m = 0; m < 4; ++m)
#pragma unroll
                for (int n = 0; n < 4; ++n)
                    acc[m][n] = __builtin_amdgcn_mfma_f32_16x16x32_bf16(ah[m], bh[n], acc[m][n], 0, 0, 0);
#pragma unroll
            for (int m = 0; m < 4; ++m)
#pragma unroll
                for (int n = 0; n < 4; ++n)
                    acc[m][n] = __builtin_amdgcn_mfma_f32_16x16x32_bf16(al[m], bh[n], acc[m][n], 0, 0, 0);
#pragma unroll
            for (int m = 0; m < 4; ++m)
#pragma unroll
                for (int n = 0; n < 4; ++n)
                    acc[m][n] = __builtin_amdgcn_mfma_f32_16x16x32_bf16(ah[m], bl[n], acc[m][n], 0, 0, 0);
        }
    }
    // epilogue: split to hi/lo, store into variant slot k+1; fused row sumsq -> a2
#pragma unroll
    for (int m = 0; m < 4; ++m)
#pragma unroll
        for (int j = 0; j < 4; ++j) {
            size_t row = (size_t)(k + 1) * NPT + rb + wr + m * 16 + lg * 4 + j;
            float s2 = 0.f;
#pragma unroll
            for (int n = 0; n < 4; ++n) {
                float s = acc[m][n][j];
                s2 += s * s;
                u16 h, l;
                split_hl(s, h, l);
                size_t idx = row * DIM + eb + wc + n * 16 + l15;
                outH[idx] = h;
                outL[idx] = l;
            }
            s2 += __shfl_xor(s2, 1);
            s2 += __shfl_xor(s2, 2);
            s2 += __shfl_xor(s2, 4);
            s2 += __shfl_xor(s2, 8);
            if (l15 == 0) atomicAdd(&a2out[row], s2);
        }
}

// ---------- main fused corr via bf16 MFMA hi/lo (3 terms), 9 variants ----------
// R7 version (known good): grid (32,32); XCD -> 8x16 rectangle for L2 residency;
// K=64 chunks, single-buffer 2-barrier loop, 8-chunk XOR swizzle.
// Epilogue computes per-block softmax partials (max,sum) per row/col.
__global__ __launch_bounds__(256, 2) void corr_mfma_kernel(
    const u16* __restrict__ Ahi, const u16* __restrict__ Alo,
    const u16* __restrict__ Bhi, const u16* __restrict__ Blo,
    const float* __restrict__ a2, const float* __restrict__ b2,
    float* __restrict__ cOut, unsigned* __restrict__ rm_rep, unsigned* __restrict__ cm_rep,
    float* __restrict__ pMaxR, float* __restrict__ pSumR,
    float* __restrict__ pMaxC, float* __restrict__ pSumC) {
    __shared__ u16 lds[32768];  // 64 KB
    u16* LAh = lds;
    u16* LAl = lds + 8192;
    u16* LBh = lds + 16384;
    u16* LBl = lds + 24576;

    const int tid = threadIdx.x, lane = tid & 63, wave = tid >> 6;
    const int l15 = lane & 15, lg = lane >> 4;
    const int wr = (wave >> 1) * 64, wc = (wave & 1) * 64;
    // XCD-aware swizzle: each of 8 XCDs owns an 8rb x 16cb rectangle.
    int wg = blockIdx.y * 32 + blockIdx.x;
    const int xcd = wg & 7, idx8 = wg >> 3;
    const int rbIdx = ((xcd >> 1) << 3) + (idx8 >> 4);   // 0..31
    const int cbIdx = ((xcd & 1) << 4) + (idx8 & 15);    // 0..31
    const int rb = rbIdx << 7;
    const int cb = cbIdx << 7;
    const int s_row = tid >> 3;
    const int s_ch = tid & 7;
    const int s_gch = s_ch ^ (s_row & 7);
    const int c0 = lg ^ (l15 & 7);

    float b2c[4];
#pragma unroll
    for (int n = 0; n < 4; ++n) b2c[n] = b2[cb + wc + n * 16 + l15];

    f32x4 zmin[4][4];
#pragma unroll
    for (int m = 0; m < 4; ++m)
#pragma unroll
        for (int n = 0; n < 4; ++n) zmin[m][n] = 3.402823466e38f;

    for (int v = 0; v < NVAR; ++v) {
        const u16* Ah_g = Ahi + (size_t)v * NPT * DIM;
        const u16* Al_g = Alo + (size_t)v * NPT * DIM;
        f32x4 acc[4][4];
#pragma unroll
        for (int m = 0; m < 4; ++m)
#pragma unroll
            for (int n = 0; n < 4; ++n) acc[m][n] = 0.0f;

        for (int kb = 0; kb < 4; ++kb) {
            const int k0 = kb * 64;
            __syncthreads();
#pragma unroll
            for (int r = 0; r < 4; ++r) {
                int row = r * 32 + s_row;
                size_t ga = (size_t)(rb + row) * DIM + k0 + s_gch * 8;
                size_t gb = (size_t)(cb + row) * DIM + k0 + s_gch * 8;
                int lo = row * 64 + s_ch * 8;
                gl_lds16(Ah_g + ga, &LAh[lo]);
                gl_lds16(Al_g + ga, &LAl[lo]);
                gl_lds16(Bhi + gb, &LBh[lo]);
                gl_lds16(Blo + gb, &LBl[lo]);
            }
            __syncthreads();
#pragma unroll
            for (int ks = 0; ks < 2; ++ks) {
                const int cx = (c0 ^ (ks << 2)) * 8;
                bf16x8 ah[4], al[4], bh[4], bl[4];
#pragma unroll
                for (int m = 0; m < 4; ++m) {
                    int ro = (wr + m * 16 + l15) * 64 + cx;
                    ah[m] = *(const bf16x8*)&LAh[ro];
                    al[m] = *(const bf16x8*)&LAl[ro];
                }
#pragma unroll
                for (int n = 0; n < 4; ++n) {
                    int ro = (wc + n * 16 + l15) * 64 + cx;
                    bh[n] = *(const bf16x8*)&LBh[ro];
                    bl[n] = *(const bf16x8*)&LBl[ro];
                }
#pragma unroll
                for (int m = 0; m < 4; ++m)
#pragma unroll
                    for (int n = 0; n < 4; ++n)
                        acc[m][n] = __builtin_amdgcn_mfma_f32_16x16x32_bf16(ah[m], bh[n], acc[m][n], 0, 0, 0);
#pragma unroll
                for (int m = 0; m < 4; ++m)
#pragma unroll
                    for (int n = 0; n < 4; ++n)
                        acc[m][n] = __builtin_amdgcn_mfma_f32_16x16x32_bf16(al[m], bh[n], acc[m][n], 0, 0, 0);
#pragma unroll
                for (int m = 0; m < 4; ++m)
#pragma unroll
                    for (int n = 0; n < 4; ++n)
                        acc[m][n] = __builtin_amdgcn_mfma_f32_16x16x32_bf16(ah[m], bl[n], acc[m][n], 0, 0, 0);
            }
        }
        // fold: d2 = a2 + b2 - 2*dot, clamp, min over variants
#pragma unroll
        for (int m = 0; m < 4; ++m) {
            float4 a4 = *(const float4*)&a2[(size_t)v * NPT + rb + wr + m * 16 + lg * 4];
            const float* a4p = (const float*)&a4;
#pragma unroll
            for (int n = 0; n < 4; ++n)
#pragma unroll
                for (int j = 0; j < 4; ++j) {
                    float d2 = fmaxf(a4p[j] + b2c[n] - 2.0f * acc[m][n][j], 0.0f);
                    zmin[m][n][j] = fminf(zmin[m][n][j], d2);
                }
        }
    }

    // ---- epilogue pass 1: c = -20*sqrt(zmin+eps), store C, block-local row/col max ----
    unsigned* redR = (unsigned*)lds;          // 128
    unsigned* redC = redR + 128;              // 128
    float* bsumR = (float*)(redC + 128);      // 128
    float* bsumC = bsumR + 128;               // 128
    __syncthreads();
    if (tid < 128) { redR[tid] = 0u; redC[tid] = 0u; bsumR[tid] = 0.f; bsumC[tid] = 0.f; }
    __syncthreads();

    float colmax[4] = {-3.402823466e38f, -3.402823466e38f, -3.402823466e38f, -3.402823466e38f};
#pragma unroll
    for (int m = 0; m < 4; ++m) {
#pragma unroll
        for (int j = 0; j < 4; ++j) {
            int row = rb + wr + m * 16 + lg * 4 + j;
            float rmax = -3.402823466e38f;
#pragma unroll
            for (int n = 0; n < 4; ++n) {
                float c = -INV_TEMP * sqrtf(zmin[m][n][j] + EPSD);
                cOut[(size_t)row * NPT + cb + wc + n * 16 + l15] = c;
                rmax = fmaxf(rmax, c);
                colmax[n] = fmaxf(colmax[n], c);
            }
            atomicMax(&redR[wr + m * 16 + lg * 4 + j], frep(rmax));
        }
    }
#pragma unroll
    for (int n = 0; n < 4; ++n)
        atomicMax(&redC[wc + n * 16 + l15], frep(colmax[n]));
    __syncthreads();

    // ---- epilogue pass 2: block-local exp-sums relative to block max ----
    float bmc[4], colS[4];
#pragma unroll
    for (int n = 0; n < 4; ++n) {
        bmc[n] = funrep(redC[wc + n * 16 + l15]);
        colS[n] = 0.f;
    }
#pragma unroll
    for (int m = 0; m < 4; ++m) {
#pragma unroll
        for (int j = 0; j < 4; ++j) {
            int lr = wr + m * 16 + lg * 4 + j;
            float bm = funrep(redR[lr]);
            float s = 0.f;
#pragma unroll
            for (int n = 0; n < 4; ++n) {
                float c = -INV_TEMP * sqrtf(zmin[m][n][j] + EPSD);
                s += __expf(c - bm);
                colS[n] += __expf(c - bmc[n]);
            }
            // reduce over the 16-lane l15 group (covers 64 cols of this row)
            s += __shfl_xor(s, 1);
            s += __shfl_xor(s, 2);
            s += __shfl_xor(s, 4);
            s += __shfl_xor(s, 8);
            if (l15 == 0) atomicAdd(&bsumR[lr], s);
        }
    }
#pragma unroll
    for (int n = 0; n < 4; ++n) {
        float s = colS[n];
        // reduce over lg (lanes differing in bits 4,5)
        s += __shfl_xor(s, 16);
        s += __shfl_xor(s, 32);
        if (lg == 0) atomicAdd(&bsumC[wc + n * 16 + l15], s);
    }
    __syncthreads();

    // ---- epilogue pass 3: global max atomics + per-block partial writes ----
    if (tid < 128) {
        atomicMax(&rm_rep[rb + tid], redR[tid]);
        pMaxR[(size_t)cbIdx * NPT + rb + tid] = funrep(redR[tid]);
        pSumR[(size_t)cbIdx * NPT + rb + tid] = bsumR[tid];
    } else {
        int t = tid - 128;
        atomicMax(&cm_rep[cb + t], redC[t]);
        pMaxC[(size_t)rbIdx * NPT + cb + t] = funrep(redC[t]);
        pSumC[(size_t)rbIdx * NPT + cb + t] = bsumC[t];
    }
}

// ======================= streaming epilogue =======================
// grid 1024 blocks; block owns 256 cols x 64 rows. Thread: 4 consecutive cols
// (c0 + lane*4), rows r0 + it*4 + wv, it=0..15. float4 I/O throughout.

// pass A: combine partials -> denominators (in-block), then
// P = exp(2c - cm - rm)/(cs*rs) in place, track row/col max of P
__global__ __launch_bounds__(256) void pmax_kernel(float* __restrict__ C,
                                                   const unsigned* __restrict__ rm_rep,
                                                   const unsigned* __restrict__ cm_rep,
                                                   const float* __restrict__ pMaxR,
                                                   const float* __restrict__ pSumR,
                                                   const float* __restrict__ pMaxC,
                                                   const float* __restrict__ pSumC,
                                                   unsigned* __restrict__ rmp_rep,
                                                   unsigned* __restrict__ cmp_rep) {
    const int tid = threadIdx.x, lane = tid & 63, wv = tid >> 6;
    const int c0 = (blockIdx.x & 15) * 256;
    const int r0 = (blockIdx.x >> 4) * 64;
    const int colq = (c0 >> 2) + lane;
    __shared__ float rmbuf[64], rrbuf[64];
    __shared__ float cmbuf[256], ccbuf[256];
    __shared__ float pmLds[64 * 65];
    __shared__ float qred[256];
    __shared__ float cred[4][256];
    // in-block combine: row denominators (64 rows) and col denominators (256 cols)
    if (tid < 64) {
        int row = r0 + tid;
        float gm = funrep(rm_rep[row]);
        float s = 0.f;
#pragma unroll
        for (int b = 0; b < 32; ++b)
            s += pSumR[(size_t)b * NPT + row] * __expf(pMaxR[(size_t)b * NPT + row] - gm);
        rmbuf[tid] = gm;
        rrbuf[tid] = 1.0f / s;
    }
    {
        int col = c0 + tid;
        float gm = funrep(cm_rep[col]);
        float s = 0.f;
#pragma unroll
        for (int b = 0; b < 32; ++b)
            s += pSumC[(size_t)b * NPT + col] * __expf(pMaxC[(size_t)b * NPT + col] - gm);
        cmbuf[tid] = gm;
        ccbuf[tid] = 1.0f / s;
    }
    __syncthreads();
    float cm0 = cmbuf[lane * 4 + 0], cm1 = cmbuf[lane * 4 + 1],
          cm2 = cmbuf[lane * 4 + 2], cm3 = cmbuf[lane * 4 + 3];
    float rc0 = ccbuf[lane * 4 + 0], rc1 = ccbuf[lane * 4 + 1],
          rc2 = ccbuf[lane * 4 + 2], rc3 = ccbuf[lane * 4 + 3];
    float4 cmax = make_float4(-1.f, -1.f, -1.f, -1.f);
#pragma unroll
    for (int it = 0; it < 16; ++it) {
        int lr = it * 4 + wv;
        int r = r0 + lr;
        size_t idx = (size_t)r * (NPT / 4) + colq;
        float4 cv = ((const float4*)C)[idx];
        float rm = rmbuf[lr];
        float rr = rrbuf[lr];
        float4 p;
        p.x = __expf(2.0f * cv.x - cm0 - rm) * (rc0 * rr);
        p.y = __expf(2.0f * cv.y - cm1 - rm) * (rc1 * rr);
        p.z = __expf(2.0f * cv.z - cm2 - rm) * (rc2 * rr);
        p.w = __expf(2.0f * cv.w - cm3 - rm) * (rc3 * rr);
        ((float4*)C)[idx] = p;
        pmLds[lr * 65 + lane] = fmaxf(fmaxf(p.x, p.y), fmaxf(p.z, p.w));
        cmax.x = fmaxf(cmax.x, p.x);
        cmax.y = fmaxf(cmax.y, p.y);
        cmax.z = fmaxf(cmax.z, p.z);
        cmax.w = fmaxf(cmax.w, p.w);
    }
    cred[wv][lane * 4 + 0] = cmax.x;
    cred[wv][lane * 4 + 1] = cmax.y;
    cred[wv][lane * 4 + 2] = cmax.z;
    cred[wv][lane * 4 + 3] = cmax.w;
    __syncthreads();
    {
        int row = tid & 63, q = tid >> 6;
        float m = -1.f;
#pragma unroll
        for (int i = 0; i < 16; ++i) m = fmaxf(m, pmLds[row * 65 + q * 16 + i]);
        qred[row * 4 + q] = m;
    }
    float mc = fmaxf(fmaxf(cred[0][tid], cred[1][tid]), fmaxf(cred[2][tid], cred[3][tid]));
    atomicMax(&cmp_rep[c0 + tid], frep(mc));
    __syncthreads();
    if (tid < 64) {
        float m = fmaxf(fmaxf(qred[tid * 4 + 0], qred[tid * 4 + 1]),
                        fmaxf(qred[tid * 4 + 2], qred[tid * 4 + 3]));
        atomicMax(&rmp_rep[r0 + tid], frep(m));
    }
}

// pass B: mask write + first-occurrence argmax (atomicMin on col index)
__global__ __launch_bounds__(256) void maskarg_kernel(const float* __restrict__ P,
                                                      const unsigned* __restrict__ rmp_rep,
                                                      const unsigned* __restrict__ cmp_rep,
                                                      float* __restrict__ maskOut,
                                                      int* __restrict__ argJ) {
    const int tid = threadIdx.x, lane = tid & 63, wv = tid >> 6;
    const int c0 = (blockIdx.x & 15) * 256;
    const int r0 = (blockIdx.x >> 4) * 64;
    const int colq = (c0 >> 2) + lane;
    const int col4 = c0 + lane * 4;
    __shared__ float rpbuf[64];
    __shared__ int candLds[64 * 65];
    __shared__ int qredi[256];
    if (tid < 64) rpbuf[tid] = funrep(rmp_rep[r0 + tid]);
    uint4 cpr = ((const uint4*)cmp_rep)[colq];
    float cp0 = funrep(cpr.x), cp1 = funrep(cpr.y), cp2 = funrep(cpr.z), cp3 = funrep(cpr.w);
    __syncthreads();
#pragma unroll
    for (int it = 0; it < 16; ++it) {
        int lr = it * 4 + wv;
        int r = r0 + lr;
        size_t idx = (size_t)r * (NPT / 4) + colq;
        float4 p = ((const float4*)P)[idx];
        float rmp = rpbuf[lr];
        float4 m;
        m.x = (p.x == rmp && p.x == cp0 && p.x > THR) ? 1.f : 0.f;
        m.y = (p.y == rmp && p.y == cp1 && p.y > THR) ? 1.f : 0.f;
        m.z = (p.z == rmp && p.z == cp2 && p.z > THR) ? 1.f : 0.f;
        m.w = (p.w == rmp && p.w == cp3 && p.w > THR) ? 1.f : 0.f;
        ((float4*)maskOut)[idx] = m;
        int cand = 0x7fffffff;
        if (p.w == rmp) cand = col4 + 3;
        if (p.z == rmp) cand = col4 + 2;
        if (p.y == rmp) cand = col4 + 1;
        if (p.x == rmp) cand = col4 + 0;
        candLds[lr * 65 + lane] = cand;
    }
    __syncthreads();
    {
        int row = tid & 63, q = tid >> 6;
        int m = 0x7fffffff;
#pragma unroll
        for (int i = 0; i < 16; ++i) m = min(m, candLds[row * 65 + q * 16 + i]);
        qredi[row * 4 + q] = m;
    }
    __syncthreads();
    if (tid < 64) {
        int m = min(min(qredi[tid * 4 + 0], qredi[tid * 4 + 1]),
                    min(qredi[tid * 4 + 2], qredi[tid * 4 + 3]));
        atomicMin(&argJ[r0 + tid], m);
    }
}

// pass C: valid flag + matched keypoints (tiny)
__global__ __launch_bounds__(256) void valid_kernel(const float* __restrict__ P,
                                                    const unsigned* __restrict__ cmp_rep,
                                                    const int* __restrict__ argJ,
                                                    const float* __restrict__ kpB,
                                                    float* __restrict__ validOut,
                                                    float* __restrict__ matchOut) {
    int n = blockIdx.x * 256 + threadIdx.x;
    int j = argJ[n];
    float pj = P[(size_t)n * NPT + j];
    bool v = (pj == funrep(cmp_rep[j])) && (pj > THR);
    validOut[n] = v ? 1.f : 0.f;
    matchOut[2 * n + 0] = kpB[2 * j + 0];
    matchOut[2 * n + 1] = kpB[2 * j + 1];
}

extern "C" void kernel_launch(void* const* d_in, const int* in_sizes, int n_in,
                              void* d_out, int out_size, void* d_ws, size_t ws_size,
                              hipStream_t stream) {
    const float* dA     = (const float*)d_in[1];  // descriptions_A [4096,256]
    const float* kpB    = (const float*)d_in[2];  // keypoints_B    [4096,2]
    const float* dB     = (const float*)d_in[3];  // descriptions_B [4096,256]
    const float* protos = (const float*)d_in[4];  // prototype_mats [8,256,256]

    float* P      = (float*)d_out;                  // 4096*4096
    float* maskO  = P + (size_t)NPT * NPT;          // 4096*4096
    float* validO = maskO + (size_t)NPT * NPT;      // 4096
    float* matchO = validO + NPT;                   // 4096*2

    // bf16 hi/lo buffers + softmax partials parked in the mask region
    // (mask written only by maskarg at the very end): ~46 MB < 64 MB
    u16* Ahi = (u16*)maskO;                         // 9*4096*256
    u16* Alo = Ahi + (size_t)NVAR * NPT * DIM;
    u16* Bhi = Alo + (size_t)NVAR * NPT * DIM;      // 4096*256
    u16* Blo = Bhi + (size_t)NPT * DIM;
    u16* Phi = Blo + (size_t)NPT * DIM;             // 8*256*256
    u16* Plo = Phi + (size_t)8 * DIM * DIM;
    float* pMaxR = (float*)(Plo + (size_t)8 * DIM * DIM);  // [32][4096]
    float* pSumR = pMaxR + 32 * NPT;
    float* pMaxC = pSumR + 32 * NPT;
    float* pSumC = pMaxC + 32 * NPT;

    // small stats live in ws (~230 KB)
    float* ws      = (float*)d_ws;
    float* a2      = ws;                 // 9*4096
    float* b2      = a2 + NVAR * NPT;    // 4096
    unsigned* rm   = (unsigned*)(b2 + NPT);   // rm|cm|rmp|cmp contiguous x4
    unsigned* cm   = rm + NPT;
    unsigned* rmp  = cm + NPT;
    unsigned* cmp  = rmp + NPT;
    int* argJ      = (int*)(cmp + NPT);

    // all zero-init folded into conv3 tail blocks (no hipMemsetAsync dispatches)
    conv3_kernel<<<2768, 256, 0, stream>>>(dA, dB, protos, Ahi, Alo, Bhi, Blo, Phi, Plo,
                                           a2, b2, rm, argJ);
    steer_mfma_kernel<<<dim3(32, 2, 8), 256, 0, stream>>>(Ahi, Alo, Phi, Plo, Ahi, Alo, a2);
    corr_mfma_kernel<<<dim3(32, 32), 256, 0, stream>>>(Ahi, Alo, Bhi, Blo, a2, b2, P, rm, cm,
                                                       pMaxR, pSumR, pMaxC, pSumC);
    pmax_kernel<<<1024, 256, 0, stream>>>(P, rm, cm, pMaxR, pSumR, pMaxC, pSumC, rmp, cmp);
    maskarg_kernel<<<1024, 256, 0, stream>>>(P, rmp, cmp, maskO, argJ);
    valid_kernel<<<16, 256, 0, stream>>>(P, cmp, argJ, kpB, validO, matchO);
}